// Round 4
// baseline (56.333 us; speedup 1.0000x reference)
//
#include <hip/hip_runtime.h>

#define DEG 32
#define NIDX 33          // DEG + self
#define F 256
#define F4 (F / 4)       // 64 float4 per row == one wave
#define RPB 4            // rows (waves) per 256-thread block
#define B1 17            // first load batch
#define B2 16            // second load batch

__global__ __launch_bounds__(256) void aggregator_kernel(
    const int* __restrict__ nodes,
    const int* __restrict__ nbr,
    const float* __restrict__ feats,
    float* __restrict__ out,
    int B)
{
    const int tid  = threadIdx.x;
    const int wave = tid >> 6;    // 0..3  -> row within block
    const int lane = tid & 63;    // float4 column chunk
    const int b    = blockIdx.x * RPB + wave;

    __shared__ int   s_idx[RPB][NIDX];
    __shared__ float s_w[RPB][NIDX];

    // ---- stage indices: 4 rows x 33 entries, one thread each ----
    const int r = tid / NIDX;
    const int d = tid - r * NIDX;
    if (tid < RPB * NIDX) {
        const int bb = blockIdx.x * RPB + r;
        int v = 0;
        if (bb < B) v = (d < DEG) ? nbr[(size_t)bb * DEG + d] : nodes[bb];
        s_idx[r][d] = v;
    }
    __syncthreads();

    // ---- first-occurrence weights (quadratic scan, 33^2 trivial) ----
    if (tid < RPB * NIDX) {
        const int v = s_idx[r][d];
        float w = 1.0f;
        for (int j = 0; j < d; ++j) {
            if (s_idx[r][j] == v) { w = 0.0f; break; }
        }
        s_w[r][d] = w;
    }
    __syncthreads();

    if (b >= B) return;

    // ---- wave-uniform indices/weights -> SGPRs (saddr-form loads) ----
    int   base[NIDX];
    float w[NIDX];
    float den = 0.0f;
    #pragma unroll
    for (int k = 0; k < NIDX; ++k) {
        base[k] = __builtin_amdgcn_readfirstlane(s_idx[wave][k]);
        w[k]    = __int_as_float(__builtin_amdgcn_readfirstlane(__float_as_int(s_w[wave][k])));
        den    += w[k];
    }

    float4 acc = make_float4(0.f, 0.f, 0.f, 0.f);
    float4 v[B1];

    // ---- batch 1: 17 loads all in flight before first use ----
    #pragma unroll
    for (int k = 0; k < B1; ++k) {
        const float4* p = (const float4*)(feats + (size_t)base[k] * F);
        v[k] = p[lane];
    }
    #pragma unroll
    for (int k = 0; k < B1; ++k) {
        acc.x = fmaf(w[k], v[k].x, acc.x);
        acc.y = fmaf(w[k], v[k].y, acc.y);
        acc.z = fmaf(w[k], v[k].z, acc.z);
        acc.w = fmaf(w[k], v[k].w, acc.w);
    }

    // ---- batch 2: remaining 16 ----
    #pragma unroll
    for (int k = 0; k < B2; ++k) {
        const float4* p = (const float4*)(feats + (size_t)base[B1 + k] * F);
        v[k] = p[lane];
    }
    #pragma unroll
    for (int k = 0; k < B2; ++k) {
        acc.x = fmaf(w[B1 + k], v[k].x, acc.x);
        acc.y = fmaf(w[B1 + k], v[k].y, acc.y);
        acc.z = fmaf(w[B1 + k], v[k].z, acc.z);
        acc.w = fmaf(w[B1 + k], v[k].w, acc.w);
    }

    const float inv = 1.0f / den;
    float4 o;
    o.x = acc.x * inv; o.y = acc.y * inv; o.z = acc.z * inv; o.w = acc.w * inv;
    ((float4*)out)[(size_t)b * F4 + lane] = o;
}

extern "C" void kernel_launch(void* const* d_in, const int* in_sizes, int n_in,
                              void* d_out, int out_size, void* d_ws, size_t ws_size,
                              hipStream_t stream)
{
    const int*   nodes = (const int*)d_in[0];
    const int*   nbr   = (const int*)d_in[1];
    const float* feats = (const float*)d_in[2];
    float*       out   = (float*)d_out;

    const int B = in_sizes[0];  // 10000

    const int grid = (B + RPB - 1) / RPB;
    aggregator_kernel<<<grid, 256, 0, stream>>>(nodes, nbr, feats, out, B);
}

// Round 5
// 52.443 us; speedup vs baseline: 1.0742x; 1.0742x over previous
//
#include <hip/hip_runtime.h>

#define DEG 32
#define NIDX 33   // DEG + self
#define F 256

__global__ __launch_bounds__(256) void aggregator_kernel(
    const int* __restrict__ nodes,
    const int* __restrict__ nbr,
    const float* __restrict__ feats,
    float* __restrict__ out,
    int B)
{
    const int b    = blockIdx.x;      // one output row per block
    const int tid  = threadIdx.x;     // 0..255 == feature column
    const int wid  = tid >> 6;        // wave 0..3
    const int lane = tid & 63;

    __shared__ int   s_idx[NIDX];
    __shared__ float s_w[NIDX];
    __shared__ float s_feat[NIDX][F];  // 33 KB row buffer

    // ---- stage the 33 indices ----
    if (tid < NIDX)
        s_idx[tid] = (tid < DEG) ? nbr[(size_t)b * DEG + tid] : nodes[b];
    __syncthreads();

    // ---- async DMA: each wave stages rows wid, wid+4, ... (1 KB per instr,
    //      zero VGPR cost, all 33 loads in the vmcnt queue) ----
    for (int d = wid; d < NIDX; d += 4) {
        const float* g = feats + (size_t)s_idx[d] * F + lane * 4;  // 16 B per lane
        __builtin_amdgcn_global_load_lds(
            (const __attribute__((address_space(1))) void*)g,
            (__attribute__((address_space(3))) void*)&s_feat[d][0],
            16 /*bytes per lane*/, 0, 0);
    }

    // ---- dedup weights while DMA is in flight ----
    if (tid < NIDX) {
        const int v = s_idx[tid];
        float w = 1.0f;
        for (int j = 0; j < tid; ++j)
            if (s_idx[j] == v) { w = 0.0f; break; }
        s_w[tid] = w;
    }
    __syncthreads();   // compiler drains vmcnt(0)+lgkmcnt(0) before s_barrier

    // ---- accumulate column tid: stride-1 ds_read_b32, conflict-free ----
    float acc = 0.0f, den = 0.0f;
    #pragma unroll
    for (int d = 0; d < NIDX; ++d) {
        const float w = s_w[d];
        den += w;
        acc = fmaf(w, s_feat[d][tid], acc);
    }
    out[(size_t)b * F + tid] = acc / den;
}

extern "C" void kernel_launch(void* const* d_in, const int* in_sizes, int n_in,
                              void* d_out, int out_size, void* d_ws, size_t ws_size,
                              hipStream_t stream)
{
    const int*   nodes = (const int*)d_in[0];
    const int*   nbr   = (const int*)d_in[1];
    const float* feats = (const float*)d_in[2];
    float*       out   = (float*)d_out;

    const int B = in_sizes[0];  // 10000

    aggregator_kernel<<<B, 256, 0, stream>>>(nodes, nbr, feats, out, B);
}